// Round 3
// baseline (289.554 us; speedup 1.0000x reference)
//
#include <hip/hip_runtime.h>

#define N_TOK 8192
#define D_IN 384
#define D_H 64
#define NHEADS 4
#define NSPLIT 4
#define N_CLS 6
#define LN_EPS 1e-5f

typedef __attribute__((ext_vector_type(8))) short short8;
typedef __attribute__((ext_vector_type(4))) float f32x4;

#define L2E2 2.08136898100560774f   /* (log2 e)^2 */

__device__ __forceinline__ unsigned short f2bf(float f) {
    unsigned int u = __float_as_uint(f);
    u += 0x7FFFu + ((u >> 16) & 1u);          // RNE (finite values only here)
    return (unsigned short)(u >> 16);
}
__device__ __forceinline__ float bf2f(unsigned short s) {
    return __uint_as_float(((unsigned int)s) << 16);
}

// Permuted key position within a 64-key tile (pairs bf16 cols for packed LDS
// writes in flash). P-columns and V-rows share the bijection -> PV invariant.
__device__ __forceinline__ int kperm(int k) {
    return (k & 32) + 2 * (k & 15) + ((k >> 4) & 1);
}

// ---------------------------------------------------------------------------
// Fused stage 1 (r9's proven version). 256 blocks x 512 thr:
// phase 1: 8 waves x 4 rows each -> h in LDS; phase 2: wave wv -> head wv>>1,
// half wv&1 (16 rows). Outputs: hp bf16 coalesced; Vf bf16 key-permuted
// coalesced b128; ssq2 = (sum hp^2)*(log2 e)^2.
// NO cooperative / fence / finisher variants: r10 (grid.sync) and r12
// (per-block threadfence) both flushed L2 device-wide and lost 2-3x.
// ---------------------------------------------------------------------------
__global__ __launch_bounds__(512) void stage1_kernel(
    const float* __restrict__ x, const float* __restrict__ proj_w,
    const float* __restrict__ proj_b, const float* __restrict__ head_w,
    const float* __restrict__ head_b,
    unsigned short* __restrict__ hp, unsigned short* __restrict__ Vf,
    float* __restrict__ ssq2)
{
    const int lane = threadIdx.x & 63;
    const int wv   = threadIdx.x >> 6;       // 0..7
    const int rb0  = blockIdx.x * 32;

    __shared__ float h_sh[32][68];                          // [row][feat]
    __shared__ __align__(16) unsigned short vt[NHEADS][4][64][8];

    // ---- phase 1: h = relu(x @ proj_w + b), 4 rows per wave ----
    {
        float acc[4];
        float b = proj_b[lane];
        #pragma unroll
        for (int r = 0; r < 4; ++r) acc[r] = b;
        const float* x0 = x + (size_t)(rb0 + wv * 4) * D_IN;
        #pragma unroll 2
        for (int k4 = 0; k4 < D_IN / 4; ++k4) {
            float w0 = proj_w[(k4 * 4 + 0) * 64 + lane];
            float w1 = proj_w[(k4 * 4 + 1) * 64 + lane];
            float w2 = proj_w[(k4 * 4 + 2) * 64 + lane];
            float w3 = proj_w[(k4 * 4 + 3) * 64 + lane];
            #pragma unroll
            for (int r = 0; r < 4; ++r) {
                float4 xv = *(const float4*)(x0 + r * D_IN + k4 * 4); // wave-uniform
                acc[r] = fmaf(xv.x, w0, acc[r]);
                acc[r] = fmaf(xv.y, w1, acc[r]);
                acc[r] = fmaf(xv.z, w2, acc[r]);
                acc[r] = fmaf(xv.w, w3, acc[r]);
            }
        }
        #pragma unroll
        for (int r = 0; r < 4; ++r)
            h_sh[wv * 4 + r][lane] = fmaxf(acc[r], 0.f);
    }
    __syncthreads();

    // ---- phase 2: hp = h @ head_w[head] + head_b[head]; 16 rows per wave ----
    const int head = wv >> 1;
    const int half = wv & 1;
    float a[16];
    {
        float b = head_b[head * 64 + lane];
        #pragma unroll
        for (int r = 0; r < 16; ++r) a[r] = b;
    }
    const float* wb = head_w + head * 64 * 64;
    #pragma unroll 2
    for (int e4 = 0; e4 < 16; ++e4) {
        float w0 = wb[(e4 * 4 + 0) * 64 + lane];
        float w1 = wb[(e4 * 4 + 1) * 64 + lane];
        float w2 = wb[(e4 * 4 + 2) * 64 + lane];
        float w3 = wb[(e4 * 4 + 3) * 64 + lane];
        #pragma unroll
        for (int r = 0; r < 16; ++r) {
            float4 hv = *(const float4*)&h_sh[half * 16 + r][e4 * 4]; // uniform b128
            a[r] = fmaf(hv.x, w0, a[r]);
            a[r] = fmaf(hv.y, w1, a[r]);
            a[r] = fmaf(hv.z, w2, a[r]);
            a[r] = fmaf(hv.w, w3, a[r]);
        }
    }

    #pragma unroll
    for (int r = 0; r < 16; ++r) {
        int kl  = half * 16 + r;
        int row = rb0 + kl;
        unsigned short hb = f2bf(a[r]);
        float hf = bf2f(hb);
        hp[((size_t)head * N_TOK + row) * 64 + lane] = hb;
        int p = kperm(row & 63);              // halves write disjoint even/odd
        vt[head][(p >> 3) & 3][lane][p & 7] = hb;
        float s = hf * hf;
        #pragma unroll
        for (int off = 32; off > 0; off >>= 1) s += __shfl_xor(s, off);
        if (lane == 0) ssq2[head * N_TOK + row] = s * L2E2;
    }
    __syncthreads();

    // ---- write Vf coalesced: 1024 chunks of 16B, 2 per thread ----
    const int kgbase = (rb0 & 32) ? 4 : 0;
    #pragma unroll
    for (int i = 0; i < 2; ++i) {
        int c  = threadIdx.x + 512 * i;
        int hc = c >> 8, rem = c & 255;
        int kg = rem >> 6, d = rem & 63;
        short8 v = *(const short8*)&vt[hc][kg][d][0];
        *(short8*)&Vf[(((size_t)hc * (N_TOK / 8) + (rb0 >> 6) * 8 + kgbase + kg) * 64
                       + d) * 8] = v;
    }
}

// ---------------------------------------------------------------------------
// Flash distance-attention. Base = r13 structure (proven 170 µs, 32 q-rows/
// wave, 4 waves/SIMD, no block barriers). Journal:
//  r14: 16-row/8-wave occupancy build REGRESSED 1.84x (loads/wave doubled;
//       wall tracked load count — flash is LOAD-LATENCY-bound). Don't retry.
//  r15: PV-c0 hoist before softmaxB was NEUTRAL: within-wave VALU/MFMA
//       co-issue doesn't exist; the hoist also exposed bV0 (~270 cyc).
// This round: r13 phase order restored + V loads issued one phase earlier:
//   bV0 issued after kB issue  -> cover = softmaxA + halfB MFMAs (~300 cyc)
//   bV1 issued after halfB     -> cover = softmaxB + PV-c0       (~300 cyc)
//   PV-c0 back AFTER softmaxB (aP0 d0-writes complete under halfB MFMAs)
// Cost: kB+bV0 live ranges overlap (+16 VGPR peak; est ~80 arch + 48 AGPR
// = 128 unified, edge of the 4-wave class).
// Go/no-go: OccupancyPercent ~44. If ~22 -> 256-reg class, revert.
// Max logit 0 (diagonal) -> no online rescaling. p = exp2(-sqrt(sq'));
// P packed bf16 pairs (kperm); O bf16. Grid (16 combos, 64 q-blocks);
// combo%8 -> one head per XCD.
// ---------------------------------------------------------------------------
__global__ __launch_bounds__(256, 4) void flash_kernel(
    const unsigned short* __restrict__ hp, const unsigned short* __restrict__ Vf,
    const float* __restrict__ ssq2, unsigned short* __restrict__ Og,
    float* __restrict__ Lg)
{
    const int head  = blockIdx.x & 3;        // combo = split*NHEADS+head
    const int split = blockIdx.x >> 2;
    const int q0    = blockIdx.y * 128;
    const int w     = threadIdx.x >> 6;
    const int lane  = threadIdx.x & 63;
    const int col   = lane & 15;
    const int quad  = lane >> 4;

    __shared__ __align__(16) unsigned short Psh[4][2][16][72];

    const unsigned short* hpH = hp + head * (N_TOK * 64);
    const unsigned short* VfH = Vf + head * (N_TOK * 64);
    const float* ssqH = ssq2 + head * N_TOK;

    const int rb = q0 + w * 32;              // this wave's 32 q-rows
    const bool diag_lo = ((rb >> 5) & 1) == 0;  // both s-tiles hit d0 (else d1)

    short8 aQ[2][2];
    float ssqn2[2][4];
    #pragma unroll
    for (int s = 0; s < 2; ++s) {
        const unsigned short* qrow = hpH + (rb + s * 16 + col) * 64;
        aQ[s][0] = *(const short8*)(qrow + quad * 8);
        aQ[s][1] = *(const short8*)(qrow + 32 + quad * 8);
        #pragma unroll
        for (int r = 0; r < 4; ++r)
            ssqn2[s][r] = ssqH[rb + s * 16 + quad * 4 + r];
    }

    const f32x4 zero4 = {0.f, 0.f, 0.f, 0.f};
    f32x4 accO[2][4] = {{zero4, zero4, zero4, zero4}, {zero4, zero4, zero4, zero4}};
    f32x4 accL[2] = {zero4, zero4};
    const short8 ones = {16256,16256,16256,16256,16256,16256,16256,16256}; // bf16 1.0
    const float NEG2L2 = -2.0f * L2E2;

    const int ktps = N_TOK / 64 / NSPLIT;    // 32
    const int kt0  = split * ktps;
    const int ktend = kt0 + ktps;

    // prime the software pipeline: half-A K frags + sm (key ssq) for tile kt0
    short8 kA[4];
    float smc[4];
    {
        const unsigned short* kb0 = hpH + kt0 * 4096;
        #pragma unroll
        for (int nt = 0; nt < 2; ++nt) {
            const unsigned short* kr = kb0 + (nt * 16 + col) * 64 + quad * 8;
            kA[nt * 2 + 0] = *(const short8*)kr;
            kA[nt * 2 + 1] = *(const short8*)(kr + 32);
        }
        #pragma unroll
        for (int nt = 0; nt < 4; ++nt) smc[nt] = ssqH[kt0 * 64 + nt * 16 + col];
    }

    #pragma unroll 1
    for (int kt = kt0; kt < ktend; ++kt) {
        const unsigned short* kb = hpH + kt * 4096;
        const unsigned short* vb = VfH + kt * 4096;

        // ---- half A: S for keys 0..31 — K frags + sm already in registers ----
        f32x4 aSA[2][2] = {{zero4, zero4}, {zero4, zero4}};
        #pragma unroll
        for (int nt = 0; nt < 2; ++nt) {
            aSA[0][nt] = __builtin_amdgcn_mfma_f32_16x16x32_bf16(aQ[0][0], kA[nt * 2 + 0], aSA[0][nt], 0, 0, 0);
            aSA[0][nt] = __builtin_amdgcn_mfma_f32_16x16x32_bf16(aQ[0][1], kA[nt * 2 + 1], aSA[0][nt], 0, 0, 0);
            aSA[1][nt] = __builtin_amdgcn_mfma_f32_16x16x32_bf16(aQ[1][0], kA[nt * 2 + 0], aSA[1][nt], 0, 0, 0);
            aSA[1][nt] = __builtin_amdgcn_mfma_f32_16x16x32_bf16(aQ[1][1], kA[nt * 2 + 1], aSA[1][nt], 0, 0, 0);
        }

        // half-B K loads issued here: covered by softmax-A (kA regs dead)
        short8 kB[4];
        #pragma unroll
        for (int nt = 0; nt < 2; ++nt) {
            const unsigned short* kr = kb + ((nt + 2) * 16 + col) * 64 + quad * 8;
            kB[nt * 2 + 0] = *(const short8*)kr;
            kB[nt * 2 + 1] = *(const short8*)(kr + 32);
        }
        // bV0 issued here too: cover = softmaxA + halfB MFMAs (~300 cyc)
        short8 bV0[4];
        #pragma unroll
        for (int dt = 0; dt < 4; ++dt)
            bV0[dt] = *(const short8*)(vb + (quad * 64 + dt * 16 + col) * 8);

        // softmax A -> write d0 (cols 0..31); aSA dies here
        #pragma unroll
        for (int s = 0; s < 2; ++s) {
            float pf0[4], pf1[4];
            #pragma unroll
            for (int r = 0; r < 4; ++r) {
                float sq0 = fmaf(aSA[s][0][r], NEG2L2, ssqn2[s][r] + smc[0]);
                pf0[r] = __builtin_amdgcn_exp2f(-__builtin_amdgcn_sqrtf(fmaxf(sq0, 0.f)));
                float sq1 = fmaf(aSA[s][1][r], NEG2L2, ssqn2[s][r] + smc[1]);
                pf1[r] = __builtin_amdgcn_exp2f(-__builtin_amdgcn_sqrtf(fmaxf(sq1, 0.f)));
            }
            #pragma unroll
            for (int r = 0; r < 4; ++r) {
                unsigned int d0 = __builtin_amdgcn_perm(__float_as_uint(pf1[r]),
                                                        __float_as_uint(pf0[r]), 0x07060302u);
                *(unsigned int*)&Psh[w][s][quad * 4 + r][2 * col] = d0;
            }
        }
        // diag tile, lo half: both s-tiles' fixes land in cols 0..31
        if (diag_lo && kt == (rb >> 6) && lane < 16) {
            #pragma unroll
            for (int s = 0; s < 2; ++s) {
                int t = ((rb + s * 16) >> 4) & 3;      // 0 or 1
                Psh[w][s][lane][2 * lane + (t & 1)] = 0x3F80;
            }
        }

        // ---- half B: S for keys 32..63 ----
        f32x4 aSB[2][2] = {{zero4, zero4}, {zero4, zero4}};
        #pragma unroll
        for (int nt = 0; nt < 2; ++nt) {
            aSB[0][nt] = __builtin_amdgcn_mfma_f32_16x16x32_bf16(aQ[0][0], kB[nt * 2 + 0], aSB[0][nt], 0, 0, 0);
            aSB[0][nt] = __builtin_amdgcn_mfma_f32_16x16x32_bf16(aQ[0][1], kB[nt * 2 + 1], aSB[0][nt], 0, 0, 0);
            aSB[1][nt] = __builtin_amdgcn_mfma_f32_16x16x32_bf16(aQ[1][0], kB[nt * 2 + 0], aSB[1][nt], 0, 0, 0);
            aSB[1][nt] = __builtin_amdgcn_mfma_f32_16x16x32_bf16(aQ[1][1], kB[nt * 2 + 1], aSB[1][nt], 0, 0, 0);
        }

        // bV1 issued here: cover = softmaxB + PV-c0 (~300 cyc); kB dead now
        short8 bV1[4];
        #pragma unroll
        for (int dt = 0; dt < 4; ++dt)
            bV1[dt] = *(const short8*)(vb + ((4 + quad) * 64 + dt * 16 + col) * 8);

        // softmax B -> write d1 (cols 32..63); aSB dies here
        #pragma unroll
        for (int s = 0; s < 2; ++s) {
            float pf2[4], pf3[4];
            #pragma unroll
            for (int r = 0; r < 4; ++r) {
                float sq2 = fmaf(aSB[s][0][r], NEG2L2, ssqn2[s][r] + smc[2]);
                pf2[r] = __builtin_amdgcn_exp2f(-__builtin_amdgcn_sqrtf(fmaxf(sq2, 0.f)));
                float sq3 = fmaf(aSB[s][1][r], NEG2L2, ssqn2[s][r] + smc[3]);
                pf3[r] = __builtin_amdgcn_exp2f(-__builtin_amdgcn_sqrtf(fmaxf(sq3, 0.f)));
            }
            #pragma unroll
            for (int r = 0; r < 4; ++r) {
                unsigned int d1 = __builtin_amdgcn_perm(__float_as_uint(pf3[r]),
                                                        __float_as_uint(pf2[r]), 0x07060302u);
                *(unsigned int*)&Psh[w][s][quad * 4 + r][32 + 2 * col] = d1;
            }
        }
        // diag tile, hi half: both s-tiles' fixes land in cols 32..63
        if (!diag_lo && kt == (rb >> 6) && lane < 16) {
            #pragma unroll
            for (int s = 0; s < 2; ++s) {
                int t = ((rb + s * 16) >> 4) & 3;      // 2 or 3
                Psh[w][s][lane][32 + 2 * lane + (t & 1)] = 0x3F80;
            }
        }

        // ---- PV c=0 (after softmaxB, r13 order): bV0 long since landed ----
        {
            short8 aP0 = *(const short8*)&Psh[w][0][col][quad * 8];
            short8 aP1 = *(const short8*)&Psh[w][1][col][quad * 8];
            accL[0] = __builtin_amdgcn_mfma_f32_16x16x32_bf16(aP0, ones, accL[0], 0, 0, 0);
            accL[1] = __builtin_amdgcn_mfma_f32_16x16x32_bf16(aP1, ones, accL[1], 0, 0, 0);
            #pragma unroll
            for (int dt = 0; dt < 4; ++dt) {
                accO[0][dt] = __builtin_amdgcn_mfma_f32_16x16x32_bf16(aP0, bV0[dt], accO[0][dt], 0, 0, 0);
                accO[1][dt] = __builtin_amdgcn_mfma_f32_16x16x32_bf16(aP1, bV0[dt], accO[1][dt], 0, 0, 0);
            }
        }

        // ---- prefetch next tile's half-A K frags + sm (kA regs free) ----
        {
            const int ktn = (kt + 1 < ktend) ? kt + 1 : kt0;
            const unsigned short* kbn = hpH + ktn * 4096;
            #pragma unroll
            for (int nt = 0; nt < 2; ++nt) {
                const unsigned short* kr = kbn + (nt * 16 + col) * 64 + quad * 8;
                kA[nt * 2 + 0] = *(const short8*)kr;
                kA[nt * 2 + 1] = *(const short8*)(kr + 32);
            }
            #pragma unroll
            for (int nt = 0; nt < 4; ++nt) smc[nt] = ssqH[ktn * 64 + nt * 16 + col];
        }

        // ---- PV c=1: bV1 covered by softmaxB + PV-c0 ----
        {
            short8 aP0b = *(const short8*)&Psh[w][0][col][32 + quad * 8];
            short8 aP1b = *(const short8*)&Psh[w][1][col][32 + quad * 8];
            accL[0] = __builtin_amdgcn_mfma_f32_16x16x32_bf16(aP0b, ones, accL[0], 0, 0, 0);
            accL[1] = __builtin_amdgcn_mfma_f32_16x16x32_bf16(aP1b, ones, accL[1], 0, 0, 0);
            #pragma unroll
            for (int dt = 0; dt < 4; ++dt) {
                accO[0][dt] = __builtin_amdgcn_mfma_f32_16x16x32_bf16(aP0b, bV1[dt], accO[0][dt], 0, 0, 0);
                accO[1][dt] = __builtin_amdgcn_mfma_f32_16x16x32_bf16(aP1b, bV1[dt], accO[1][dt], 0, 0, 0);
            }
        }
    }

    // ---- epilogue: unnormalized O (bf16) and l (f32) for this split ----
    unsigned short* og = Og + (size_t)(split * NHEADS + head) * N_TOK * 64;
    float* lg = Lg + (size_t)(split * NHEADS + head) * N_TOK;
    #pragma unroll
    for (int s = 0; s < 2; ++s)
        #pragma unroll
        for (int r = 0; r < 4; ++r) {
            int row = rb + s * 16 + quad * 4 + r;
            #pragma unroll
            for (int dt = 0; dt < 4; ++dt)
                og[row * 64 + dt * 16 + col] = f2bf(accO[s][dt][r]);
            if (col == 0) lg[row] = accL[s][r];
        }
}

// ---------------------------------------------------------------------------
// Combine: merge NSPLIT splits, head-softmax mix, layernorm, FC. Wave per row.
// ---------------------------------------------------------------------------
__global__ __launch_bounds__(256) void combine_kernel(
    const unsigned short* __restrict__ Og, const float* __restrict__ Lg,
    const float* __restrict__ attn_w, const float* __restrict__ gamma,
    const float* __restrict__ beta, const float* __restrict__ fc_w,
    const float* __restrict__ fc_b, float* __restrict__ out)
{
    const int lane = threadIdx.x & 63;
    const int ty   = threadIdx.x >> 6;
    const int row  = blockIdx.x * 4 + ty;

    float a0 = attn_w[0], a1 = attn_w[1], a2 = attn_w[2], a3 = attn_w[3];
    float m = fmaxf(fmaxf(a0, a1), fmaxf(a2, a3));
    float e0 = __expf(a0 - m), e1 = __expf(a1 - m), e2 = __expf(a2 - m), e3 = __expf(a3 - m);
    float inv = 1.f / (e0 + e1 + e2 + e3);
    float aw[4] = {e0 * inv, e1 * inv, e2 * inv, e3 * inv};

    float c = 0.f;
    #pragma unroll
    for (int hh = 0; hh < NHEADS; ++hh) {
        float l = 0.f, o = 0.f;
        #pragma unroll
        for (int s = 0; s < NSPLIT; ++s) {
            l += Lg[(s * NHEADS + hh) * N_TOK + row];
            o += bf2f(Og[(size_t)((s * NHEADS + hh) * N_TOK + row) * 64 + lane]);
        }
        c += aw[hh] * o * __builtin_amdgcn_rcpf(l);
    }

    float s = c;
    #pragma unroll
    for (int off = 32; off > 0; off >>= 1) s += __shfl_xor(s, off);
    float mu = s * (1.f / 64.f);
    float d = c - mu;
    float v = d * d;
    #pragma unroll
    for (int off = 32; off > 0; off >>= 1) v += __shfl_xor(v, off);
    float normed = d * rsqrtf(v * (1.f / 64.f) + LN_EPS) * gamma[lane] + beta[lane];

    float lg[N_CLS];
    #pragma unroll
    for (int cc = 0; cc < N_CLS; ++cc) {
        float p = normed * fc_w[lane * N_CLS + cc];
        #pragma unroll
        for (int off = 32; off > 0; off >>= 1) p += __shfl_xor(p, off);
        lg[cc] = p;
    }
    if (lane == 0) {
        #pragma unroll
        for (int cc = 0; cc < N_CLS; ++cc)
            out[row * N_CLS + cc] = lg[cc] + fc_b[cc];
    }
}

// ---------------------------------------------------------------------------
extern "C" void kernel_launch(void* const* d_in, const int* in_sizes, int n_in,
                              void* d_out, int out_size, void* d_ws, size_t ws_size,
                              hipStream_t stream)
{
    const float* x      = (const float*)d_in[0];
    const float* proj_w = (const float*)d_in[1];
    const float* proj_b = (const float*)d_in[2];
    const float* head_w = (const float*)d_in[3];
    const float* head_b = (const float*)d_in[4];
    const float* attn_w = (const float*)d_in[5];
    const float* gamma  = (const float*)d_in[6];
    const float* beta   = (const float*)d_in[7];
    const float* fc_w   = (const float*)d_in[8];
    const float* fc_b   = (const float*)d_in[9];
    float* out = (float*)d_out;

    char* ws = (char*)d_ws;
    // ws layout (bytes):
    //   hp   bf16 [4][8192][64]        @ 0          (4 MB)
    //   Vf   bf16 [4][1024][64][8]     @ 4 MB       (4 MB, key-permuted)
    //   ssq2 f32  [4][8192]            @ 8 MB       (128 KB)
    //   Og   bf16 [4][4][8192][64]     @ 8M+128K    (16 MB)
    //   Lg   f32  [4][4][8192]         @ 24M+128K   (512 KB)
    unsigned short* hp = (unsigned short*)(ws);
    unsigned short* Vf = (unsigned short*)(ws + (4u << 20));
    float* ssq2 = (float*)(ws + (8u << 20));
    unsigned short* Og = (unsigned short*)(ws + (8u << 20) + (128u << 10));
    float* Lg   = (float*)(ws + (24u << 20) + (128u << 10));

    stage1_kernel<<<N_TOK / 32, 512, 0, stream>>>(x, proj_w, proj_b, head_w, head_b,
                                                  hp, Vf, ssq2);
    dim3 g2(NHEADS * NSPLIT, N_TOK / 128);  // combo fastest -> one head per XCD
    flash_kernel<<<g2, 256, 0, stream>>>(hp, Vf, ssq2, Og, Lg);
    combine_kernel<<<N_TOK / 4, 256, 0, stream>>>(Og, Lg, attn_w, gamma, beta,
                                                  fc_w, fc_b, out);
}

// Round 4
// 229.409 us; speedup vs baseline: 1.2622x; 1.2622x over previous
//
#include <hip/hip_runtime.h>

#define N_TOK 8192
#define D_IN 384
#define D_H 64
#define NHEADS 4
#define NSPLIT 3
#define N_CLS 6
#define LN_EPS 1e-5f

typedef __attribute__((ext_vector_type(8))) short short8;
typedef __attribute__((ext_vector_type(4))) float f32x4;

#define L2E2 2.08136898100560774f   /* (log2 e)^2 */

__device__ __forceinline__ unsigned short f2bf(float f) {
    unsigned int u = __float_as_uint(f);
    u += 0x7FFFu + ((u >> 16) & 1u);          // RNE (finite values only here)
    return (unsigned short)(u >> 16);
}
__device__ __forceinline__ float bf2f(unsigned short s) {
    return __uint_as_float(((unsigned int)s) << 16);
}

// Permuted key position within a 64-key tile (pairs bf16 cols for packed LDS
// writes in flash). P-columns and V-rows share the bijection -> PV invariant.
__device__ __forceinline__ int kperm(int k) {
    return (k & 32) + 2 * (k & 15) + ((k >> 4) & 1);
}

// ---------------------------------------------------------------------------
// Fused stage 1 (r9's proven version). 256 blocks x 512 thr:
// phase 1: 8 waves x 4 rows each -> h in LDS; phase 2: wave wv -> head wv>>1,
// half wv&1 (16 rows). Outputs: hp bf16 coalesced; Vf bf16 key-permuted
// coalesced b128; ssq2 = (sum hp^2)*(log2 e)^2.
// NO cooperative / fence / finisher variants: r10 (grid.sync) and r12
// (per-block threadfence) both flushed L2 device-wide and lost 2-3x.
// ---------------------------------------------------------------------------
__global__ __launch_bounds__(512) void stage1_kernel(
    const float* __restrict__ x, const float* __restrict__ proj_w,
    const float* __restrict__ proj_b, const float* __restrict__ head_w,
    const float* __restrict__ head_b,
    unsigned short* __restrict__ hp, unsigned short* __restrict__ Vf,
    float* __restrict__ ssq2)
{
    const int lane = threadIdx.x & 63;
    const int wv   = threadIdx.x >> 6;       // 0..7
    const int rb0  = blockIdx.x * 32;

    __shared__ float h_sh[32][68];                          // [row][feat]
    __shared__ __align__(16) unsigned short vt[NHEADS][4][64][8];

    // ---- phase 1: h = relu(x @ proj_w + b), 4 rows per wave ----
    {
        float acc[4];
        float b = proj_b[lane];
        #pragma unroll
        for (int r = 0; r < 4; ++r) acc[r] = b;
        const float* x0 = x + (size_t)(rb0 + wv * 4) * D_IN;
        #pragma unroll 2
        for (int k4 = 0; k4 < D_IN / 4; ++k4) {
            float w0 = proj_w[(k4 * 4 + 0) * 64 + lane];
            float w1 = proj_w[(k4 * 4 + 1) * 64 + lane];
            float w2 = proj_w[(k4 * 4 + 2) * 64 + lane];
            float w3 = proj_w[(k4 * 4 + 3) * 64 + lane];
            #pragma unroll
            for (int r = 0; r < 4; ++r) {
                float4 xv = *(const float4*)(x0 + r * D_IN + k4 * 4); // wave-uniform
                acc[r] = fmaf(xv.x, w0, acc[r]);
                acc[r] = fmaf(xv.y, w1, acc[r]);
                acc[r] = fmaf(xv.z, w2, acc[r]);
                acc[r] = fmaf(xv.w, w3, acc[r]);
            }
        }
        #pragma unroll
        for (int r = 0; r < 4; ++r)
            h_sh[wv * 4 + r][lane] = fmaxf(acc[r], 0.f);
    }
    __syncthreads();

    // ---- phase 2: hp = h @ head_w[head] + head_b[head]; 16 rows per wave ----
    const int head = wv >> 1;
    const int half = wv & 1;
    float a[16];
    {
        float b = head_b[head * 64 + lane];
        #pragma unroll
        for (int r = 0; r < 16; ++r) a[r] = b;
    }
    const float* wb = head_w + head * 64 * 64;
    #pragma unroll 2
    for (int e4 = 0; e4 < 16; ++e4) {
        float w0 = wb[(e4 * 4 + 0) * 64 + lane];
        float w1 = wb[(e4 * 4 + 1) * 64 + lane];
        float w2 = wb[(e4 * 4 + 2) * 64 + lane];
        float w3 = wb[(e4 * 4 + 3) * 64 + lane];
        #pragma unroll
        for (int r = 0; r < 16; ++r) {
            float4 hv = *(const float4*)&h_sh[half * 16 + r][e4 * 4]; // uniform b128
            a[r] = fmaf(hv.x, w0, a[r]);
            a[r] = fmaf(hv.y, w1, a[r]);
            a[r] = fmaf(hv.z, w2, a[r]);
            a[r] = fmaf(hv.w, w3, a[r]);
        }
    }

    #pragma unroll
    for (int r = 0; r < 16; ++r) {
        int kl  = half * 16 + r;
        int row = rb0 + kl;
        unsigned short hb = f2bf(a[r]);
        float hf = bf2f(hb);
        hp[((size_t)head * N_TOK + row) * 64 + lane] = hb;
        int p = kperm(row & 63);              // halves write disjoint even/odd
        vt[head][(p >> 3) & 3][lane][p & 7] = hb;
        float s = hf * hf;
        #pragma unroll
        for (int off = 32; off > 0; off >>= 1) s += __shfl_xor(s, off);
        if (lane == 0) ssq2[head * N_TOK + row] = s * L2E2;
    }
    __syncthreads();

    // ---- write Vf coalesced: 1024 chunks of 16B, 2 per thread ----
    const int kgbase = (rb0 & 32) ? 4 : 0;
    #pragma unroll
    for (int i = 0; i < 2; ++i) {
        int c  = threadIdx.x + 512 * i;
        int hc = c >> 8, rem = c & 255;
        int kg = rem >> 6, d = rem & 63;
        short8 v = *(const short8*)&vt[hc][kg][d][0];
        *(short8*)&Vf[(((size_t)hc * (N_TOK / 8) + (rb0 >> 6) * 8 + kgbase + kg) * 64
                       + d) * 8] = v;
    }
}

// ---------------------------------------------------------------------------
// Flash distance-attention, LDS-STAGED build. Journal:
//  r13 (170µs): per-wave global K/V loads (16 b128/ktile), 4 blk/CU. Best of
//       the reg-prefetch family.
//  r14: 16-row/8-wave occupancy REGRESSED 1.84x (loads/wave doubled; wall
//       tracks per-wave global-load count).
//  r15/r16: earlier-issue reorders NEUTRAL->WORSE; FETCH grew 6.3->9.4MB
//       (more in-flight lines -> L2 reuse window thrash). Micro-scheduling
//       of global loads is a dead end on this kernel.
// This round (structural, T14 async-STAGE): all 4 waves share each 8KB K and
// V tile -> stage both in LDS once per block. Reg-staged split: issue 4 b128
// global loads at tile top, compute whole tile, ds_write + 1 barrier at tile
// end (HBM latency hidden under ~3K cyc of compute). Per-wave-ktile global
// VMEM 20 -> 9. K stored XOR-swizzled (j ^= row&7): unswizzled b128 col-reads
// are 16-way conflicts; swizzled = 8-way BW floor (optimal for b128). V tile
// layout already BW-floor in its global (kperm'd) order -> staged linear.
// LDS 50KB (Psh 18K + 2x8K K + 2x8K V) -> 3 blk/CU, so NSPLIT=3: grid
// 12 combos x 64 qblocks = 768 = exactly 3/CU, zero tail; (combo+4y)&7 still
// pins one head per XCD. Per SIMD: 3 waves from 3 DIFFERENT blocks ->
// barriers desynchronized across blocks.
// Max logit 0 (diagonal) -> no online rescaling. p = exp2(-sqrt(sq'));
// P packed bf16 pairs (kperm); O bf16.
// Go/no-go: flash < 170µs else revert to r13 structure.
// ---------------------------------------------------------------------------
__global__ __launch_bounds__(256, 4) void flash_kernel(
    const unsigned short* __restrict__ hp, const unsigned short* __restrict__ Vf,
    const float* __restrict__ ssq2, unsigned short* __restrict__ Og,
    float* __restrict__ Lg)
{
    const int head  = blockIdx.x & 3;        // combo = split*NHEADS+head
    const int split = blockIdx.x >> 2;       // 0..2
    const int q0    = blockIdx.y * 128;
    const int w     = threadIdx.x >> 6;
    const int lane  = threadIdx.x & 63;
    const int col   = lane & 15;
    const int quad  = lane >> 4;
    const int tid   = threadIdx.x;

    __shared__ __align__(16) unsigned short Psh[4][2][16][72];
    __shared__ __align__(16) unsigned short Kst[2][4096];   // XOR-swizzled
    __shared__ __align__(16) unsigned short Vst[2][4096];   // linear (Vf order)

    const unsigned short* hpH = hp + head * (N_TOK * 64);
    const unsigned short* VfH = Vf + head * (N_TOK * 64);
    const float* ssqH = ssq2 + head * N_TOK;

    const int rb = q0 + w * 32;              // this wave's 32 q-rows
    const bool diag_lo = ((rb >> 5) & 1) == 0;  // both s-tiles hit d0 (else d1)

    short8 aQ[2][2];
    float ssqn2[2][4];
    #pragma unroll
    for (int s = 0; s < 2; ++s) {
        const unsigned short* qrow = hpH + (rb + s * 16 + col) * 64;
        aQ[s][0] = *(const short8*)(qrow + quad * 8);
        aQ[s][1] = *(const short8*)(qrow + 32 + quad * 8);
        #pragma unroll
        for (int r = 0; r < 4; ++r)
            ssqn2[s][r] = ssqH[rb + s * 16 + quad * 4 + r];
    }

    const f32x4 zero4 = {0.f, 0.f, 0.f, 0.f};
    f32x4 accO[2][4] = {{zero4, zero4, zero4, zero4}, {zero4, zero4, zero4, zero4}};
    f32x4 accL[2] = {zero4, zero4};
    const short8 ones = {16256,16256,16256,16256,16256,16256,16256,16256}; // bf16 1.0
    const float NEG2L2 = -2.0f * L2E2;

    // staging offsets. K chunk c (16B) lives at ((c&~7)|((c&7)^((c>>3)&7)))*16
    const int koff0 = (((tid & ~7) | ((tid & 7) ^ ((tid >> 3) & 7))) << 4);
    // K frag read base: row=col (+nt*16), j=quad (f0) / 4+quad (f1), swizzled
    const int karow = col * 128 + ((quad ^ (col & 7)) << 4);   // f1 = ^64
    const int va    = (quad * 64 + col) << 4;                  // V chunk base

    const int kt0   = (split * 128) / NSPLIT;        // 0,42,85
    const int ktend = ((split + 1) * 128) / NSPLIT;  // 42,85,128

    short8 stK0, stK1, stV0, stV1;
    // ---- prologue: stage tile kt0 -> buf 0 (latency exposed once) ----
    {
        const unsigned short* kg = hpH + kt0 * 4096;
        const unsigned short* vg = VfH + kt0 * 4096;
        stK0 = *(const short8*)(kg + tid * 8);
        stK1 = *(const short8*)(kg + tid * 8 + 2048);
        stV0 = *(const short8*)(vg + tid * 8);
        stV1 = *(const short8*)(vg + tid * 8 + 2048);
        *(short8*)((char*)&Kst[0][0] + koff0)        = stK0;
        *(short8*)((char*)&Kst[0][0] + koff0 + 4096) = stK1;
        *(short8*)((char*)&Vst[0][0] + tid * 16)        = stV0;
        *(short8*)((char*)&Vst[0][0] + tid * 16 + 4096) = stV1;
    }
    float smc[4];
    #pragma unroll
    for (int nt = 0; nt < 4; ++nt) smc[nt] = ssqH[kt0 * 64 + nt * 16 + col];
    __syncthreads();

    #pragma unroll 1
    for (int kt = kt0; kt < ktend; ++kt) {
        const int b = (kt - kt0) & 1;
        const char* Kb = (const char*)&Kst[b][0];
        const char* Vb = (const char*)&Vst[b][0];
        const bool has_next = (kt + 1 < ktend);

        // ---- issue next tile's staging loads + next sm (consumed at tile end)
        float smn[4];
        if (has_next) {
            const unsigned short* kg = hpH + (kt + 1) * 4096;
            const unsigned short* vg = VfH + (kt + 1) * 4096;
            stK0 = *(const short8*)(kg + tid * 8);
            stK1 = *(const short8*)(kg + tid * 8 + 2048);
            stV0 = *(const short8*)(vg + tid * 8);
            stV1 = *(const short8*)(vg + tid * 8 + 2048);
            #pragma unroll
            for (int nt = 0; nt < 4; ++nt)
                smn[nt] = ssqH[(kt + 1) * 64 + nt * 16 + col];
        }

        // ---- half A: S for keys 0..31 (K frags from LDS) ----
        f32x4 aSA[2][2] = {{zero4, zero4}, {zero4, zero4}};
        {
            short8 k0 = *(const short8*)(Kb + karow);
            short8 k1 = *(const short8*)(Kb + (karow ^ 64));
            short8 k2 = *(const short8*)(Kb + 2048 + karow);
            short8 k3 = *(const short8*)(Kb + 2048 + (karow ^ 64));
            aSA[0][0] = __builtin_amdgcn_mfma_f32_16x16x32_bf16(aQ[0][0], k0, aSA[0][0], 0, 0, 0);
            aSA[0][0] = __builtin_amdgcn_mfma_f32_16x16x32_bf16(aQ[0][1], k1, aSA[0][0], 0, 0, 0);
            aSA[1][0] = __builtin_amdgcn_mfma_f32_16x16x32_bf16(aQ[1][0], k0, aSA[1][0], 0, 0, 0);
            aSA[1][0] = __builtin_amdgcn_mfma_f32_16x16x32_bf16(aQ[1][1], k1, aSA[1][0], 0, 0, 0);
            aSA[0][1] = __builtin_amdgcn_mfma_f32_16x16x32_bf16(aQ[0][0], k2, aSA[0][1], 0, 0, 0);
            aSA[0][1] = __builtin_amdgcn_mfma_f32_16x16x32_bf16(aQ[0][1], k3, aSA[0][1], 0, 0, 0);
            aSA[1][1] = __builtin_amdgcn_mfma_f32_16x16x32_bf16(aQ[1][0], k2, aSA[1][1], 0, 0, 0);
            aSA[1][1] = __builtin_amdgcn_mfma_f32_16x16x32_bf16(aQ[1][1], k3, aSA[1][1], 0, 0, 0);
        }

        // softmax A -> write d0 (cols 0..31); aSA dies here
        #pragma unroll
        for (int s = 0; s < 2; ++s) {
            float pf0[4], pf1[4];
            #pragma unroll
            for (int r = 0; r < 4; ++r) {
                float sq0 = fmaf(aSA[s][0][r], NEG2L2, ssqn2[s][r] + smc[0]);
                pf0[r] = __builtin_amdgcn_exp2f(-__builtin_amdgcn_sqrtf(fmaxf(sq0, 0.f)));
                float sq1 = fmaf(aSA[s][1][r], NEG2L2, ssqn2[s][r] + smc[1]);
                pf1[r] = __builtin_amdgcn_exp2f(-__builtin_amdgcn_sqrtf(fmaxf(sq1, 0.f)));
            }
            #pragma unroll
            for (int r = 0; r < 4; ++r) {
                unsigned int d0 = __builtin_amdgcn_perm(__float_as_uint(pf1[r]),
                                                        __float_as_uint(pf0[r]), 0x07060302u);
                *(unsigned int*)&Psh[w][s][quad * 4 + r][2 * col] = d0;
            }
        }
        // diag tile, lo half: both s-tiles' fixes land in cols 0..31
        if (diag_lo && kt == (rb >> 6) && lane < 16) {
            #pragma unroll
            for (int s = 0; s < 2; ++s) {
                int t = ((rb + s * 16) >> 4) & 3;      // 0 or 1
                Psh[w][s][lane][2 * lane + (t & 1)] = 0x3F80;
            }
        }

        // ---- half B: S for keys 32..63 ----
        f32x4 aSB[2][2] = {{zero4, zero4}, {zero4, zero4}};
        {
            short8 k0 = *(const short8*)(Kb + 4096 + karow);
            short8 k1 = *(const short8*)(Kb + 4096 + (karow ^ 64));
            short8 k2 = *(const short8*)(Kb + 6144 + karow);
            short8 k3 = *(const short8*)(Kb + 6144 + (karow ^ 64));
            aSB[0][0] = __builtin_amdgcn_mfma_f32_16x16x32_bf16(aQ[0][0], k0, aSB[0][0], 0, 0, 0);
            aSB[0][0] = __builtin_amdgcn_mfma_f32_16x16x32_bf16(aQ[0][1], k1, aSB[0][0], 0, 0, 0);
            aSB[1][0] = __builtin_amdgcn_mfma_f32_16x16x32_bf16(aQ[1][0], k0, aSB[1][0], 0, 0, 0);
            aSB[1][0] = __builtin_amdgcn_mfma_f32_16x16x32_bf16(aQ[1][1], k1, aSB[1][0], 0, 0, 0);
            aSB[0][1] = __builtin_amdgcn_mfma_f32_16x16x32_bf16(aQ[0][0], k2, aSB[0][1], 0, 0, 0);
            aSB[0][1] = __builtin_amdgcn_mfma_f32_16x16x32_bf16(aQ[0][1], k3, aSB[0][1], 0, 0, 0);
            aSB[1][1] = __builtin_amdgcn_mfma_f32_16x16x32_bf16(aQ[1][0], k2, aSB[1][1], 0, 0, 0);
            aSB[1][1] = __builtin_amdgcn_mfma_f32_16x16x32_bf16(aQ[1][1], k3, aSB[1][1], 0, 0, 0);
        }

        // softmax B -> write d1 (cols 32..63); aSB dies here
        #pragma unroll
        for (int s = 0; s < 2; ++s) {
            float pf2[4], pf3[4];
            #pragma unroll
            for (int r = 0; r < 4; ++r) {
                float sq2 = fmaf(aSB[s][0][r], NEG2L2, ssqn2[s][r] + smc[2]);
                pf2[r] = __builtin_amdgcn_exp2f(-__builtin_amdgcn_sqrtf(fmaxf(sq2, 0.f)));
                float sq3 = fmaf(aSB[s][1][r], NEG2L2, ssqn2[s][r] + smc[3]);
                pf3[r] = __builtin_amdgcn_exp2f(-__builtin_amdgcn_sqrtf(fmaxf(sq3, 0.f)));
            }
            #pragma unroll
            for (int r = 0; r < 4; ++r) {
                unsigned int d1 = __builtin_amdgcn_perm(__float_as_uint(pf3[r]),
                                                        __float_as_uint(pf2[r]), 0x07060302u);
                *(unsigned int*)&Psh[w][s][quad * 4 + r][32 + 2 * col] = d1;
            }
        }
        // diag tile, hi half: both s-tiles' fixes land in cols 32..63
        if (!diag_lo && kt == (rb >> 6) && lane < 16) {
            #pragma unroll
            for (int s = 0; s < 2; ++s) {
                int t = ((rb + s * 16) >> 4) & 3;      // 2 or 3
                Psh[w][s][lane][32 + 2 * lane + (t & 1)] = 0x3F80;
            }
        }

        // ---- PV c=0 (V from LDS) ----
        {
            short8 aP0 = *(const short8*)&Psh[w][0][col][quad * 8];
            short8 aP1 = *(const short8*)&Psh[w][1][col][quad * 8];
            short8 bV[4];
            #pragma unroll
            for (int dt = 0; dt < 4; ++dt)
                bV[dt] = *(const short8*)(Vb + va + dt * 256);
            accL[0] = __builtin_amdgcn_mfma_f32_16x16x32_bf16(aP0, ones, accL[0], 0, 0, 0);
            accL[1] = __builtin_amdgcn_mfma_f32_16x16x32_bf16(aP1, ones, accL[1], 0, 0, 0);
            #pragma unroll
            for (int dt = 0; dt < 4; ++dt) {
                accO[0][dt] = __builtin_amdgcn_mfma_f32_16x16x32_bf16(aP0, bV[dt], accO[0][dt], 0, 0, 0);
                accO[1][dt] = __builtin_amdgcn_mfma_f32_16x16x32_bf16(aP1, bV[dt], accO[1][dt], 0, 0, 0);
            }
        }
        // ---- PV c=1 ----
        {
            short8 aP0b = *(const short8*)&Psh[w][0][col][32 + quad * 8];
            short8 aP1b = *(const short8*)&Psh[w][1][col][32 + quad * 8];
            short8 bV[4];
            #pragma unroll
            for (int dt = 0; dt < 4; ++dt)
                bV[dt] = *(const short8*)(Vb + va + dt * 256 + 4096);
            accL[0] = __builtin_amdgcn_mfma_f32_16x16x32_bf16(aP0b, ones, accL[0], 0, 0, 0);
            accL[1] = __builtin_amdgcn_mfma_f32_16x16x32_bf16(aP1b, ones, accL[1], 0, 0, 0);
            #pragma unroll
            for (int dt = 0; dt < 4; ++dt) {
                accO[0][dt] = __builtin_amdgcn_mfma_f32_16x16x32_bf16(aP0b, bV[dt], accO[0][dt], 0, 0, 0);
                accO[1][dt] = __builtin_amdgcn_mfma_f32_16x16x32_bf16(aP1b, bV[dt], accO[1][dt], 0, 0, 0);
            }
        }

        // ---- write staged tile kt+1 into buf b^1; 1 barrier per tile ----
        if (has_next) {
            char* Kn = (char*)&Kst[b ^ 1][0];
            char* Vn = (char*)&Vst[b ^ 1][0];
            *(short8*)(Kn + koff0)        = stK0;
            *(short8*)(Kn + koff0 + 4096) = stK1;
            *(short8*)(Vn + tid * 16)        = stV0;
            *(short8*)(Vn + tid * 16 + 4096) = stV1;
        }
        __syncthreads();
        if (has_next) {
            smc[0] = smn[0]; smc[1] = smn[1]; smc[2] = smn[2]; smc[3] = smn[3];
        }
    }

    // ---- epilogue: unnormalized O (bf16) and l (f32) for this split ----
    unsigned short* og = Og + (size_t)(split * NHEADS + head) * N_TOK * 64;
    float* lg = Lg + (size_t)(split * NHEADS + head) * N_TOK;
    #pragma unroll
    for (int s = 0; s < 2; ++s)
        #pragma unroll
        for (int r = 0; r < 4; ++r) {
            int row = rb + s * 16 + quad * 4 + r;
            #pragma unroll
            for (int dt = 0; dt < 4; ++dt)
                og[row * 64 + dt * 16 + col] = f2bf(accO[s][dt][r]);
            if (col == 0) lg[row] = accL[s][r];
        }
}

// ---------------------------------------------------------------------------
// Combine: merge NSPLIT splits, head-softmax mix, layernorm, FC. Wave per row.
// ---------------------------------------------------------------------------
__global__ __launch_bounds__(256) void combine_kernel(
    const unsigned short* __restrict__ Og, const float* __restrict__ Lg,
    const float* __restrict__ attn_w, const float* __restrict__ gamma,
    const float* __restrict__ beta, const float* __restrict__ fc_w,
    const float* __restrict__ fc_b, float* __restrict__ out)
{
    const int lane = threadIdx.x & 63;
    const int ty   = threadIdx.x >> 6;
    const int row  = blockIdx.x * 4 + ty;

    float a0 = attn_w[0], a1 = attn_w[1], a2 = attn_w[2], a3 = attn_w[3];
    float m = fmaxf(fmaxf(a0, a1), fmaxf(a2, a3));
    float e0 = __expf(a0 - m), e1 = __expf(a1 - m), e2 = __expf(a2 - m), e3 = __expf(a3 - m);
    float inv = 1.f / (e0 + e1 + e2 + e3);
    float aw[4] = {e0 * inv, e1 * inv, e2 * inv, e3 * inv};

    float c = 0.f;
    #pragma unroll
    for (int hh = 0; hh < NHEADS; ++hh) {
        float l = 0.f, o = 0.f;
        #pragma unroll
        for (int s = 0; s < NSPLIT; ++s) {
            l += Lg[(s * NHEADS + hh) * N_TOK + row];
            o += bf2f(Og[(size_t)((s * NHEADS + hh) * N_TOK + row) * 64 + lane]);
        }
        c += aw[hh] * o * __builtin_amdgcn_rcpf(l);
    }

    float s = c;
    #pragma unroll
    for (int off = 32; off > 0; off >>= 1) s += __shfl_xor(s, off);
    float mu = s * (1.f / 64.f);
    float d = c - mu;
    float v = d * d;
    #pragma unroll
    for (int off = 32; off > 0; off >>= 1) v += __shfl_xor(v, off);
    float normed = d * rsqrtf(v * (1.f / 64.f) + LN_EPS) * gamma[lane] + beta[lane];

    float lg[N_CLS];
    #pragma unroll
    for (int cc = 0; cc < N_CLS; ++cc) {
        float p = normed * fc_w[lane * N_CLS + cc];
        #pragma unroll
        for (int off = 32; off > 0; off >>= 1) p += __shfl_xor(p, off);
        lg[cc] = p;
    }
    if (lane == 0) {
        #pragma unroll
        for (int cc = 0; cc < N_CLS; ++cc)
            out[row * N_CLS + cc] = lg[cc] + fc_b[cc];
    }
}

// ---------------------------------------------------------------------------
extern "C" void kernel_launch(void* const* d_in, const int* in_sizes, int n_in,
                              void* d_out, int out_size, void* d_ws, size_t ws_size,
                              hipStream_t stream)
{
    const float* x      = (const float*)d_in[0];
    const float* proj_w = (const float*)d_in[1];
    const float* proj_b = (const float*)d_in[2];
    const float* head_w = (const float*)d_in[3];
    const float* head_b = (const float*)d_in[4];
    const float* attn_w = (const float*)d_in[5];
    const float* gamma  = (const float*)d_in[6];
    const float* beta   = (const float*)d_in[7];
    const float* fc_w   = (const float*)d_in[8];
    const float* fc_b   = (const float*)d_in[9];
    float* out = (float*)d_out;

    char* ws = (char*)d_ws;
    // ws layout (bytes):
    //   hp   bf16 [4][8192][64]        @ 0          (4 MB)
    //   Vf   bf16 [4][1024][64][8]     @ 4 MB       (4 MB, key-permuted)
    //   ssq2 f32  [4][8192]            @ 8 MB       (128 KB)
    //   Og   bf16 [3][4][8192][64]     @ 8M+128K    (12 MB)
    //   Lg   f32  [3][4][8192]         @ 20M+128K   (384 KB)
    unsigned short* hp = (unsigned short*)(ws);
    unsigned short* Vf = (unsigned short*)(ws + (4u << 20));
    float* ssq2 = (float*)(ws + (8u << 20));
    unsigned short* Og = (unsigned short*)(ws + (8u << 20) + (128u << 10));
    float* Lg   = (float*)(ws + (20u << 20) + (128u << 10));

    stage1_kernel<<<N_TOK / 32, 512, 0, stream>>>(x, proj_w, proj_b, head_w, head_b,
                                                  hp, Vf, ssq2);
    dim3 g2(NHEADS * NSPLIT, N_TOK / 128);  // 12 x 64 = 768 = 3 blocks/CU exact
    flash_kernel<<<g2, 256, 0, stream>>>(hp, Vf, ssq2, Og, Lg);
    combine_kernel<<<N_TOK / 4, 256, 0, stream>>>(Og, Lg, attn_w, gamma, beta,
                                                  fc_w, fc_b, out);
}

// Round 5
// 219.776 us; speedup vs baseline: 1.3175x; 1.0438x over previous
//
#include <hip/hip_runtime.h>

#define N_TOK 8192
#define D_IN 384
#define D_H 64
#define NHEADS 4
#define NSPLIT 4
#define N_CLS 6
#define LN_EPS 1e-5f

typedef __attribute__((ext_vector_type(8))) short short8;
typedef __attribute__((ext_vector_type(4))) float f32x4;

#define L2E2 2.08136898100560774f   /* (log2 e)^2 */

__device__ __forceinline__ unsigned short f2bf(float f) {
    unsigned int u = __float_as_uint(f);
    u += 0x7FFFu + ((u >> 16) & 1u);          // RNE (finite values only here)
    return (unsigned short)(u >> 16);
}
__device__ __forceinline__ float bf2f(unsigned short s) {
    return __uint_as_float(((unsigned int)s) << 16);
}

// Permuted key position within a 64-key tile (pairs bf16 cols for packed LDS
// writes in flash). P-columns and V-rows share the bijection -> PV invariant.
__device__ __forceinline__ int kperm(int k) {
    return (k & 32) + 2 * (k & 15) + ((k >> 4) & 1);
}

// Direct global->LDS 16B copy. LDS dest must be wave-uniform base + lane*16
// (ours is: tid*16 => wave base + lane*16). Global source is per-lane, so
// swizzled LDS layouts are made by pre-swizzling the SOURCE (rule 21).
__device__ __forceinline__ void gload_lds16(const void* g, void* l) {
    __builtin_amdgcn_global_load_lds(
        (const __attribute__((address_space(1))) unsigned int*)g,
        (__attribute__((address_space(3))) unsigned int*)l, 16, 0, 0);
}

// ---------------------------------------------------------------------------
// Fused stage 1 (r9's proven version). 256 blocks x 512 thr:
// phase 1: 8 waves x 4 rows each -> h in LDS; phase 2: wave wv -> head wv>>1,
// half wv&1 (16 rows). Outputs: hp bf16 coalesced; Vf bf16 key-permuted
// coalesced b128; ssq2 = (sum hp^2)*(log2 e)^2.
// NO cooperative / fence / finisher variants: r10 (grid.sync) and r12
// (per-block threadfence) both flushed L2 device-wide and lost 2-3x.
// ---------------------------------------------------------------------------
__global__ __launch_bounds__(512) void stage1_kernel(
    const float* __restrict__ x, const float* __restrict__ proj_w,
    const float* __restrict__ proj_b, const float* __restrict__ head_w,
    const float* __restrict__ head_b,
    unsigned short* __restrict__ hp, unsigned short* __restrict__ Vf,
    float* __restrict__ ssq2)
{
    const int lane = threadIdx.x & 63;
    const int wv   = threadIdx.x >> 6;       // 0..7
    const int rb0  = blockIdx.x * 32;

    __shared__ float h_sh[32][68];                          // [row][feat]
    __shared__ __align__(16) unsigned short vt[NHEADS][4][64][8];

    // ---- phase 1: h = relu(x @ proj_w + b), 4 rows per wave ----
    {
        float acc[4];
        float b = proj_b[lane];
        #pragma unroll
        for (int r = 0; r < 4; ++r) acc[r] = b;
        const float* x0 = x + (size_t)(rb0 + wv * 4) * D_IN;
        #pragma unroll 2
        for (int k4 = 0; k4 < D_IN / 4; ++k4) {
            float w0 = proj_w[(k4 * 4 + 0) * 64 + lane];
            float w1 = proj_w[(k4 * 4 + 1) * 64 + lane];
            float w2 = proj_w[(k4 * 4 + 2) * 64 + lane];
            float w3 = proj_w[(k4 * 4 + 3) * 64 + lane];
            #pragma unroll
            for (int r = 0; r < 4; ++r) {
                float4 xv = *(const float4*)(x0 + r * D_IN + k4 * 4); // wave-uniform
                acc[r] = fmaf(xv.x, w0, acc[r]);
                acc[r] = fmaf(xv.y, w1, acc[r]);
                acc[r] = fmaf(xv.z, w2, acc[r]);
                acc[r] = fmaf(xv.w, w3, acc[r]);
            }
        }
        #pragma unroll
        for (int r = 0; r < 4; ++r)
            h_sh[wv * 4 + r][lane] = fmaxf(acc[r], 0.f);
    }
    __syncthreads();

    // ---- phase 2: hp = h @ head_w[head] + head_b[head]; 16 rows per wave ----
    const int head = wv >> 1;
    const int half = wv & 1;
    float a[16];
    {
        float b = head_b[head * 64 + lane];
        #pragma unroll
        for (int r = 0; r < 16; ++r) a[r] = b;
    }
    const float* wb = head_w + head * 64 * 64;
    #pragma unroll 2
    for (int e4 = 0; e4 < 16; ++e4) {
        float w0 = wb[(e4 * 4 + 0) * 64 + lane];
        float w1 = wb[(e4 * 4 + 1) * 64 + lane];
        float w2 = wb[(e4 * 4 + 2) * 64 + lane];
        float w3 = wb[(e4 * 4 + 3) * 64 + lane];
        #pragma unroll
        for (int r = 0; r < 16; ++r) {
            float4 hv = *(const float4*)&h_sh[half * 16 + r][e4 * 4]; // uniform b128
            a[r] = fmaf(hv.x, w0, a[r]);
            a[r] = fmaf(hv.y, w1, a[r]);
            a[r] = fmaf(hv.z, w2, a[r]);
            a[r] = fmaf(hv.w, w3, a[r]);
        }
    }

    #pragma unroll
    for (int r = 0; r < 16; ++r) {
        int kl  = half * 16 + r;
        int row = rb0 + kl;
        unsigned short hb = f2bf(a[r]);
        float hf = bf2f(hb);
        hp[((size_t)head * N_TOK + row) * 64 + lane] = hb;
        int p = kperm(row & 63);              // halves write disjoint even/odd
        vt[head][(p >> 3) & 3][lane][p & 7] = hb;
        float s = hf * hf;
        #pragma unroll
        for (int off = 32; off > 0; off >>= 1) s += __shfl_xor(s, off);
        if (lane == 0) ssq2[head * N_TOK + row] = s * L2E2;
    }
    __syncthreads();

    // ---- write Vf coalesced: 1024 chunks of 16B, 2 per thread ----
    const int kgbase = (rb0 & 32) ? 4 : 0;
    #pragma unroll
    for (int i = 0; i < 2; ++i) {
        int c  = threadIdx.x + 512 * i;
        int hc = c >> 8, rem = c & 255;
        int kg = rem >> 6, d = rem & 63;
        short8 v = *(const short8*)&vt[hc][kg][d][0];
        *(short8*)&Vf[(((size_t)hc * (N_TOK / 8) + (rb0 >> 6) * 8 + kgbase + kg) * 64
                       + d) * 8] = v;
    }
}

// ---------------------------------------------------------------------------
// Flash distance-attention, 32KB-LDS / 4-blocks-per-CU build. Journal:
//  r14: 16-row waves REGRESSED 1.84x (never shrink per-wave tile).
//  r15/r16: global-load reorders neutral/worse (L2 window thrash).
//  r17 (127us): LDS staging, 50KB, 3 blk/CU, 88% issue-busy, 12% stall gap.
// This round: fill the stall gap with +33% residency at IDENTICAL per-wave
// work. LDS 50->32KB: Psh [72]->[64]+XOR swizzle (read addr thread-const),
// K+V single-buffered, staged via global_load_lds w=16 (linear LDS dest;
// K source pre-swizzled — involution => content identical to r17). Two
// barriers/tile: V(t) issues at top (cover=QK+softmax, drained at MID);
// K(t+1) issues after MID (cover=PV, drained at END). NSPLIT=4 -> 1024
// blocks = 4/CU exact (capacity 5 at 32KB -> robust, no tail); one head per
// XCD preserved (xcd = combo&7, combos c and c+8 share head c&3).
// Go/no-go: flash < 127us else revert to r17.
// ---------------------------------------------------------------------------
__global__ __launch_bounds__(256, 4) void flash_kernel(
    const unsigned short* __restrict__ hp, const unsigned short* __restrict__ Vf,
    const float* __restrict__ ssq2, unsigned short* __restrict__ Og,
    float* __restrict__ Lg)
{
    const int head  = blockIdx.x & 3;        // combo = split*NHEADS+head
    const int split = blockIdx.x >> 2;       // 0..3
    const int q0    = blockIdx.y * 128;
    const int w     = threadIdx.x >> 6;
    const int lane  = threadIdx.x & 63;
    const int col   = lane & 15;
    const int quad  = lane >> 4;
    const int tid   = threadIdx.x;

    __shared__ __align__(16) unsigned short Psh[4][2][16][64]; // XOR-swizzled
    __shared__ __align__(16) unsigned short Kst[4096];         // swizzled content
    __shared__ __align__(16) unsigned short Vst[4096];         // linear (Vf order)

    const unsigned short* hpH = hp + head * (N_TOK * 64);
    const unsigned short* VfH = Vf + head * (N_TOK * 64);
    const float* ssqH = ssq2 + head * N_TOK;

    const int rb = q0 + w * 32;              // this wave's 32 q-rows
    const bool diag_lo = ((rb >> 5) & 1) == 0;  // both s-tiles hit d0 (else d1)

    short8 aQ[2][2];
    float ssqn2[2][4];
    #pragma unroll
    for (int s = 0; s < 2; ++s) {
        const unsigned short* qrow = hpH + (rb + s * 16 + col) * 64;
        aQ[s][0] = *(const short8*)(qrow + quad * 8);
        aQ[s][1] = *(const short8*)(qrow + 32 + quad * 8);
        #pragma unroll
        for (int r = 0; r < 4; ++r)
            ssqn2[s][r] = ssqH[rb + s * 16 + quad * 4 + r];
    }

    const f32x4 zero4 = {0.f, 0.f, 0.f, 0.f};
    f32x4 accO[2][4] = {{zero4, zero4, zero4, zero4}, {zero4, zero4, zero4, zero4}};
    f32x4 accL[2] = {zero4, zero4};
    const short8 ones = {16256,16256,16256,16256,16256,16256,16256,16256}; // bf16 1.0
    const float NEG2L2 = -2.0f * L2E2;

    // Staging: LDS chunk c linear; global source chunk = swz(c) (involution).
    const int koff0 = (((tid & ~7) | ((tid & 7) ^ ((tid >> 3) & 7))) << 4);
    // K/P read base (swizzled): row=col, chunk quad -> quad^(col&7). ^64 = +4 chunks.
    const int karow = col * 128 + ((quad ^ (col & 7)) << 4);
    const int va    = (quad * 64 + col) << 4;                  // V chunk base
    // Psh write base: row=quad*4+r, chunk (col>>2)^(row&7); +r*128 and ^(r<<4).
    const int wcb   = quad * 512 + ((((col >> 2) ^ ((quad & 1) << 2)) << 4))
                      + ((col & 3) << 2);

    const int kt0   = split * 32;
    const int ktend = kt0 + 32;

    // ---- prologue: stage K(kt0); latency exposed once ----
    {
        const char* kg = (const char*)(hpH + kt0 * 4096);
        gload_lds16(kg + koff0,        (char*)Kst + tid * 16);
        gload_lds16(kg + koff0 + 4096, (char*)Kst + tid * 16 + 4096);
    }
    float smc[4];
    #pragma unroll
    for (int nt = 0; nt < 4; ++nt) smc[nt] = ssqH[kt0 * 64 + nt * 16 + col];
    __syncthreads();

    #pragma unroll 1
    for (int kt = kt0; kt < ktend; ++kt) {
        const bool has_next = (kt + 1 < ktend);

        // ---- V(kt) -> Vst (prev END barrier passed => buffer free).
        //      Cover to MID barrier = QK + softmax (~1300 cyc). ----
        {
            const char* vg = (const char*)(VfH + kt * 4096);
            gload_lds16(vg + tid * 16,        (char*)Vst + tid * 16);
            gload_lds16(vg + tid * 16 + 4096, (char*)Vst + tid * 16 + 4096);
        }
        float smn[4];
        if (has_next) {
            #pragma unroll
            for (int nt = 0; nt < 4; ++nt)
                smn[nt] = ssqH[(kt + 1) * 64 + nt * 16 + col];
        }

        const char* Kb = (const char*)Kst;

        // ---- half A: S for keys 0..31 (K frags from LDS) ----
        f32x4 aSA[2][2] = {{zero4, zero4}, {zero4, zero4}};
        {
            short8 k0 = *(const short8*)(Kb + karow);
            short8 k1 = *(const short8*)(Kb + (karow ^ 64));
            short8 k2 = *(const short8*)(Kb + 2048 + karow);
            short8 k3 = *(const short8*)(Kb + 2048 + (karow ^ 64));
            aSA[0][0] = __builtin_amdgcn_mfma_f32_16x16x32_bf16(aQ[0][0], k0, aSA[0][0], 0, 0, 0);
            aSA[0][0] = __builtin_amdgcn_mfma_f32_16x16x32_bf16(aQ[0][1], k1, aSA[0][0], 0, 0, 0);
            aSA[1][0] = __builtin_amdgcn_mfma_f32_16x16x32_bf16(aQ[1][0], k0, aSA[1][0], 0, 0, 0);
            aSA[1][0] = __builtin_amdgcn_mfma_f32_16x16x32_bf16(aQ[1][1], k1, aSA[1][0], 0, 0, 0);
            aSA[0][1] = __builtin_amdgcn_mfma_f32_16x16x32_bf16(aQ[0][0], k2, aSA[0][1], 0, 0, 0);
            aSA[0][1] = __builtin_amdgcn_mfma_f32_16x16x32_bf16(aQ[0][1], k3, aSA[0][1], 0, 0, 0);
            aSA[1][1] = __builtin_amdgcn_mfma_f32_16x16x32_bf16(aQ[1][0], k2, aSA[1][1], 0, 0, 0);
            aSA[1][1] = __builtin_amdgcn_mfma_f32_16x16x32_bf16(aQ[1][1], k3, aSA[1][1], 0, 0, 0);
        }

        // softmax A -> d0 (swizzled chunk writes); aSA dies here
        #pragma unroll
        for (int s = 0; s < 2; ++s) {
            char* pB = (char*)&Psh[w][s][0][0];
            float pf0[4], pf1[4];
            #pragma unroll
            for (int r = 0; r < 4; ++r) {
                float sq0 = fmaf(aSA[s][0][r], NEG2L2, ssqn2[s][r] + smc[0]);
                pf0[r] = __builtin_amdgcn_exp2f(-__builtin_amdgcn_sqrtf(fmaxf(sq0, 0.f)));
                float sq1 = fmaf(aSA[s][1][r], NEG2L2, ssqn2[s][r] + smc[1]);
                pf1[r] = __builtin_amdgcn_exp2f(-__builtin_amdgcn_sqrtf(fmaxf(sq1, 0.f)));
            }
            #pragma unroll
            for (int r = 0; r < 4; ++r) {
                unsigned int d0 = __builtin_amdgcn_perm(__float_as_uint(pf1[r]),
                                                        __float_as_uint(pf0[r]), 0x07060302u);
                *(unsigned int*)(pB + ((wcb ^ (r << 4)) + r * 128)) = d0;
            }
        }
        // diag tile, lo half
        if (diag_lo && kt == (rb >> 6) && lane < 16) {
            #pragma unroll
            for (int s = 0; s < 2; ++s) {
                int t = ((rb + s * 16) >> 4) & 3;      // 0 or 1
                int sc2 = 4 * lane + 2 * (t & 1);
                int ad = lane * 128 + (((lane >> 2) ^ (lane & 7)) << 4) + (sc2 & 15);
                *(unsigned short*)((char*)&Psh[w][s][0][0] + ad) = 0x3F80;
            }
        }

        // ---- half B: S for keys 32..63 ----
        f32x4 aSB[2][2] = {{zero4, zero4}, {zero4, zero4}};
        {
            short8 k0 = *(const short8*)(Kb + 4096 + karow);
            short8 k1 = *(const short8*)(Kb + 4096 + (karow ^ 64));
            short8 k2 = *(const short8*)(Kb + 6144 + karow);
            short8 k3 = *(const short8*)(Kb + 6144 + (karow ^ 64));
            aSB[0][0] = __builtin_amdgcn_mfma_f32_16x16x32_bf16(aQ[0][0], k0, aSB[0][0], 0, 0, 0);
            aSB[0][0] = __builtin_amdgcn_mfma_f32_16x16x32_bf16(aQ[0][1], k1, aSB[0][0], 0, 0, 0);
            aSB[1][0] = __builtin_amdgcn_mfma_f32_16x16x32_bf16(aQ[1][0], k0, aSB[1][0], 0, 0, 0);
            aSB[1][0] = __builtin_amdgcn_mfma_f32_16x16x32_bf16(aQ[1][1], k1, aSB[1][0], 0, 0, 0);
            aSB[0][1] = __builtin_amdgcn_mfma_f32_16x16x32_bf16(aQ[0][0], k2, aSB[0][1], 0, 0, 0);
            aSB[0][1] = __builtin_amdgcn_mfma_f32_16x16x32_bf16(aQ[0][1], k3, aSB[0][1], 0, 0, 0);
            aSB[1][1] = __builtin_amdgcn_mfma_f32_16x16x32_bf16(aQ[1][0], k2, aSB[1][1], 0, 0, 0);
            aSB[1][1] = __builtin_amdgcn_mfma_f32_16x16x32_bf16(aQ[1][1], k3, aSB[1][1], 0, 0, 0);
        }

        // softmax B -> d1 (same swizzled addr ^ 64); aSB dies here
        #pragma unroll
        for (int s = 0; s < 2; ++s) {
            char* pB = (char*)&Psh[w][s][0][0];
            float pf2[4], pf3[4];
            #pragma unroll
            for (int r = 0; r < 4; ++r) {
                float sq2 = fmaf(aSB[s][0][r], NEG2L2, ssqn2[s][r] + smc[2]);
                pf2[r] = __builtin_amdgcn_exp2f(-__builtin_amdgcn_sqrtf(fmaxf(sq2, 0.f)));
                float sq3 = fmaf(aSB[s][1][r], NEG2L2, ssqn2[s][r] + smc[3]);
                pf3[r] = __builtin_amdgcn_exp2f(-__builtin_amdgcn_sqrtf(fmaxf(sq3, 0.f)));
            }
            #pragma unroll
            for (int r = 0; r < 4; ++r) {
                unsigned int d1 = __builtin_amdgcn_perm(__float_as_uint(pf3[r]),
                                                        __float_as_uint(pf2[r]), 0x07060302u);
                *(unsigned int*)(pB + (((wcb ^ (r << 4)) + r * 128) ^ 64)) = d1;
            }
        }
        // diag tile, hi half
        if (!diag_lo && kt == (rb >> 6) && lane < 16) {
            #pragma unroll
            for (int s = 0; s < 2; ++s) {
                int t = ((rb + s * 16) >> 4) & 3;      // 2 or 3
                int sc2 = 4 * lane + 2 * (t & 1);
                int ad = (lane * 128 + (((lane >> 2) ^ (lane & 7)) << 4) + (sc2 & 15)) ^ 64;
                *(unsigned short*)((char*)&Psh[w][s][0][0] + ad) = 0x3F80;
            }
        }

        // ---- MID barrier: V(kt) landed (vmcnt drain); all K reads done ----
        __syncthreads();

        // ---- K(kt+1) -> Kst (single buffer now safe); cover = PV ----
        if (has_next) {
            const char* kgn = (const char*)(hpH + (kt + 1) * 4096);
            gload_lds16(kgn + koff0,        (char*)Kst + tid * 16);
            gload_lds16(kgn + koff0 + 4096, (char*)Kst + tid * 16 + 4096);
        }

        // ---- PV c=0 ----
        {
            const char* p0 = (const char*)&Psh[w][0][0][0];
            const char* p1 = (const char*)&Psh[w][1][0][0];
            const char* Vb = (const char*)Vst;
            short8 aP0 = *(const short8*)(p0 + karow);
            short8 aP1 = *(const short8*)(p1 + karow);
            short8 bV[4];
            #pragma unroll
            for (int dt = 0; dt < 4; ++dt)
                bV[dt] = *(const short8*)(Vb + va + dt * 256);
            accL[0] = __builtin_amdgcn_mfma_f32_16x16x32_bf16(aP0, ones, accL[0], 0, 0, 0);
            accL[1] = __builtin_amdgcn_mfma_f32_16x16x32_bf16(aP1, ones, accL[1], 0, 0, 0);
            #pragma unroll
            for (int dt = 0; dt < 4; ++dt) {
                accO[0][dt] = __builtin_amdgcn_mfma_f32_16x16x32_bf16(aP0, bV[dt], accO[0][dt], 0, 0, 0);
                accO[1][dt] = __builtin_amdgcn_mfma_f32_16x16x32_bf16(aP1, bV[dt], accO[1][dt], 0, 0, 0);
            }
            // ---- PV c=1 ----
            short8 aP0b = *(const short8*)(p0 + (karow ^ 64));
            short8 aP1b = *(const short8*)(p1 + (karow ^ 64));
            #pragma unroll
            for (int dt = 0; dt < 4; ++dt)
                bV[dt] = *(const short8*)(Vb + va + dt * 256 + 4096);
            accL[0] = __builtin_amdgcn_mfma_f32_16x16x32_bf16(aP0b, ones, accL[0], 0, 0, 0);
            accL[1] = __builtin_amdgcn_mfma_f32_16x16x32_bf16(aP1b, ones, accL[1], 0, 0, 0);
            #pragma unroll
            for (int dt = 0; dt < 4; ++dt) {
                accO[0][dt] = __builtin_amdgcn_mfma_f32_16x16x32_bf16(aP0b, bV[dt], accO[0][dt], 0, 0, 0);
                accO[1][dt] = __builtin_amdgcn_mfma_f32_16x16x32_bf16(aP1b, bV[dt], accO[1][dt], 0, 0, 0);
            }
        }

        // ---- END barrier: Vst free for next top; K(kt+1) landed ----
        __syncthreads();
        if (has_next) {
            smc[0] = smn[0]; smc[1] = smn[1]; smc[2] = smn[2]; smc[3] = smn[3];
        }
    }

    // ---- epilogue: unnormalized O (bf16) and l (f32) for this split ----
    unsigned short* og = Og + (size_t)(split * NHEADS + head) * N_TOK * 64;
    float* lg = Lg + (size_t)(split * NHEADS + head) * N_TOK;
    #pragma unroll
    for (int s = 0; s < 2; ++s)
        #pragma unroll
        for (int r = 0; r < 4; ++r) {
            int row = rb + s * 16 + quad * 4 + r;
            #pragma unroll
            for (int dt = 0; dt < 4; ++dt)
                og[row * 64 + dt * 16 + col] = f2bf(accO[s][dt][r]);
            if (col == 0) lg[row] = accL[s][r];
        }
}

// ---------------------------------------------------------------------------
// Combine: merge NSPLIT splits, head-softmax mix, layernorm, FC. Wave per row.
// ---------------------------------------------------------------------------
__global__ __launch_bounds__(256) void combine_kernel(
    const unsigned short* __restrict__ Og, const float* __restrict__ Lg,
    const float* __restrict__ attn_w, const float* __restrict__ gamma,
    const float* __restrict__ beta, const float* __restrict__ fc_w,
    const float* __restrict__ fc_b, float* __restrict__ out)
{
    const int lane = threadIdx.x & 63;
    const int ty   = threadIdx.x >> 6;
    const int row  = blockIdx.x * 4 + ty;

    float a0 = attn_w[0], a1 = attn_w[1], a2 = attn_w[2], a3 = attn_w[3];
    float m = fmaxf(fmaxf(a0, a1), fmaxf(a2, a3));
    float e0 = __expf(a0 - m), e1 = __expf(a1 - m), e2 = __expf(a2 - m), e3 = __expf(a3 - m);
    float inv = 1.f / (e0 + e1 + e2 + e3);
    float aw[4] = {e0 * inv, e1 * inv, e2 * inv, e3 * inv};

    float c = 0.f;
    #pragma unroll
    for (int hh = 0; hh < NHEADS; ++hh) {
        float l = 0.f, o = 0.f;
        #pragma unroll
        for (int s = 0; s < NSPLIT; ++s) {
            l += Lg[(s * NHEADS + hh) * N_TOK + row];
            o += bf2f(Og[(size_t)((s * NHEADS + hh) * N_TOK + row) * 64 + lane]);
        }
        c += aw[hh] * o * __builtin_amdgcn_rcpf(l);
    }

    float s = c;
    #pragma unroll
    for (int off = 32; off > 0; off >>= 1) s += __shfl_xor(s, off);
    float mu = s * (1.f / 64.f);
    float d = c - mu;
    float v = d * d;
    #pragma unroll
    for (int off = 32; off > 0; off >>= 1) v += __shfl_xor(v, off);
    float normed = d * rsqrtf(v * (1.f / 64.f) + LN_EPS) * gamma[lane] + beta[lane];

    float lg[N_CLS];
    #pragma unroll
    for (int cc = 0; cc < N_CLS; ++cc) {
        float p = normed * fc_w[lane * N_CLS + cc];
        #pragma unroll
        for (int off = 32; off > 0; off >>= 1) p += __shfl_xor(p, off);
        lg[cc] = p;
    }
    if (lane == 0) {
        #pragma unroll
        for (int cc = 0; cc < N_CLS; ++cc)
            out[row * N_CLS + cc] = lg[cc] + fc_b[cc];
    }
}

// ---------------------------------------------------------------------------
extern "C" void kernel_launch(void* const* d_in, const int* in_sizes, int n_in,
                              void* d_out, int out_size, void* d_ws, size_t ws_size,
                              hipStream_t stream)
{
    const float* x      = (const float*)d_in[0];
    const float* proj_w = (const float*)d_in[1];
    const float* proj_b = (const float*)d_in[2];
    const float* head_w = (const float*)d_in[3];
    const float* head_b = (const float*)d_in[4];
    const float* attn_w = (const float*)d_in[5];
    const float* gamma  = (const float*)d_in[6];
    const float* beta   = (const float*)d_in[7];
    const float* fc_w   = (const float*)d_in[8];
    const float* fc_b   = (const float*)d_in[9];
    float* out = (float*)d_out;

    char* ws = (char*)d_ws;
    // ws layout (bytes):
    //   hp   bf16 [4][8192][64]        @ 0          (4 MB)
    //   Vf   bf16 [4][1024][64][8]     @ 4 MB       (4 MB, key-permuted)
    //   ssq2 f32  [4][8192]            @ 8 MB       (128 KB)
    //   Og   bf16 [4][4][8192][64]     @ 8M+128K    (16 MB)
    //   Lg   f32  [4][4][8192]         @ 24M+128K   (512 KB)
    unsigned short* hp = (unsigned short*)(ws);
    unsigned short* Vf = (unsigned short*)(ws + (4u << 20));
    float* ssq2 = (float*)(ws + (8u << 20));
    unsigned short* Og = (unsigned short*)(ws + (8u << 20) + (128u << 10));
    float* Lg   = (float*)(ws + (24u << 20) + (128u << 10));

    stage1_kernel<<<N_TOK / 32, 512, 0, stream>>>(x, proj_w, proj_b, head_w, head_b,
                                                  hp, Vf, ssq2);
    dim3 g2(NHEADS * NSPLIT, N_TOK / 128);  // 16 x 64 = 1024 = 4 blocks/CU exact
    flash_kernel<<<g2, 256, 0, stream>>>(hp, Vf, ssq2, Og, Lg);
    combine_kernel<<<N_TOK / 4, 256, 0, stream>>>(Og, Lg, attn_w, gamma, beta,
                                                  fc_w, fc_b, out);
}